// Round 7
// baseline (176.891 us; speedup 1.0000x reference)
//
#include <hip/hip_runtime.h>

#define NB 8          // 7 full blocks + 1 partial block
#define DDIM 2048
#define THREADS 512
#define NBLK 512      // co-resident: 2 blocks/CU x 256 CU
#define NWAVES (THREADS / 64)

typedef float f32x4 __attribute__((ext_vector_type(4)));

// 64-lane f32 add-reduction via DPP (VALU pipe, no DS ops). Total in lane 63.
__device__ __forceinline__ float wave_sum64(float x) {
    int t;
    t = __builtin_amdgcn_update_dpp(0, __float_as_int(x), 0x111, 0xf, 0xf, false); // row_shr:1
    x += __int_as_float(t);
    t = __builtin_amdgcn_update_dpp(0, __float_as_int(x), 0x112, 0xf, 0xf, false); // row_shr:2
    x += __int_as_float(t);
    t = __builtin_amdgcn_update_dpp(0, __float_as_int(x), 0x114, 0xf, 0xf, false); // row_shr:4
    x += __int_as_float(t);
    t = __builtin_amdgcn_update_dpp(0, __float_as_int(x), 0x118, 0xf, 0xf, false); // row_shr:8
    x += __int_as_float(t);
    t = __builtin_amdgcn_update_dpp(0, __float_as_int(x), 0x142, 0xa, 0xf, false); // row_bcast:15
    x += __int_as_float(t);
    t = __builtin_amdgcn_update_dpp(0, __float_as_int(x), 0x143, 0xc, 0xf, false); // row_bcast:31
    x += __int_as_float(t);
    return x;
}

// Barrier that orders LDS only — does NOT drain vmcnt, so prefetch loads
// stay in flight across it (unlike __syncthreads, which emits vmcnt(0)).
__device__ __forceinline__ void barrier_lgkm() {
    asm volatile("s_waitcnt lgkmcnt(0)" ::: "memory");
    __builtin_amdgcn_s_barrier();
}

__global__ __launch_bounds__(THREADS, 4)   // cap 128 VGPR -> 2 blocks/CU
void block_attn_res_kernel(
    const float* __restrict__ blocks,   // [7, B*T, D]
    const float* __restrict__ partial,  // [B*T, D]
    const float* __restrict__ qa,
    const float* __restrict__ qm,
    const float* __restrict__ wa,
    const float* __restrict__ wm,
    float* __restrict__ out,            // h_attn [B*T*D] then h_mlp [B*T*D]
    int BT)
{
    const int tid = threadIdx.x;
    const int b   = blockIdx.x;
    const int c   = tid * 4;                      // this thread's 4 contiguous cols
    const size_t nStride = (size_t)BT * DDIM;
    const int rpb = BT / NBLK;                    // rows per block (16)

    __shared__ float red[2][NWAVES * 24];
    __shared__ float totl[2][24];

    const f32x4 qwa = *reinterpret_cast<const f32x4*>(qa + c) *
                      *reinterpret_cast<const f32x4*>(wa + c);
    const f32x4 qwm = *reinterpret_cast<const f32x4*>(qm + c) *
                      *reinterpret_cast<const f32x4*>(wm + c);

    f32x4 vA[NB], vB[NB];

    auto rowbase = [&](int i) -> size_t {
        return (size_t)(i * NBLK + b) * DDIM + c;
    };
    auto load_row = [&](f32x4* v, size_t rb) {
#pragma unroll
        for (int n = 0; n < NB; ++n) {
            const float* src = (n < NB - 1) ? (blocks + (size_t)n * nStride + rb)
                                            : (partial + rb);
            v[n] = *reinterpret_cast<const f32x4*>(src);
        }
    };

    auto process = [&](const f32x4* v, float* redb, float* totb, size_t rb) {
        float ss[NB], da[NB], dm[NB];
#pragma unroll
        for (int n = 0; n < NB; ++n) {
            float s = 0.f, pa = 0.f, pm = 0.f;
#pragma unroll
            for (int j = 0; j < 4; ++j) {
                s  += v[n][j] * v[n][j];
                pa += qwa[j]  * v[n][j];
                pm += qwm[j]  * v[n][j];
            }
            ss[n] = wave_sum64(s);
            da[n] = wave_sum64(pa);
            dm[n] = wave_sum64(pm);
        }
        const int wave = tid >> 6;
        if ((tid & 63) == 63) {
#pragma unroll
            for (int n = 0; n < NB; ++n) {
                redb[wave * 24 + n]      = ss[n];
                redb[wave * 24 + 8 + n]  = da[n];
                redb[wave * 24 + 16 + n] = dm[n];
            }
        }
        barrier_lgkm();
        if (tid < 24) {
            float s = 0.f;
#pragma unroll
            for (int w = 0; w < NWAVES; ++w) s += redb[w * 24 + tid];
            totb[tid] = s;
        }
        barrier_lgkm();

        float t24[24];
        {
            const f32x4* t4 = reinterpret_cast<const f32x4*>(totb);
#pragma unroll
            for (int g = 0; g < 6; ++g) {
                f32x4 x = t4[g];
                t24[4 * g + 0] = x.x; t24[4 * g + 1] = x.y;
                t24[4 * g + 2] = x.z; t24[4 * g + 3] = x.w;
            }
        }

        float aw[NB], mw[NB];
        {
            const float inv_sqrt_d = rsqrtf((float)DDIM);
            float lga[NB], lgm[NB];
#pragma unroll
            for (int n = 0; n < NB; ++n) {
                float rms = rsqrtf(t24[n] * (1.0f / DDIM) + 1e-6f);
                lga[n] = t24[8 + n]  * rms * inv_sqrt_d;
                lgm[n] = t24[16 + n] * rms * inv_sqrt_d;
            }
            float ma = lga[0], mm = lgm[0];
#pragma unroll
            for (int n = 1; n < NB; ++n) { ma = fmaxf(ma, lga[n]); mm = fmaxf(mm, lgm[n]); }
            float sa = 0.f, sm = 0.f;
#pragma unroll
            for (int n = 0; n < NB; ++n) {
                aw[n] = __expf(lga[n] - ma); sa += aw[n];
                mw[n] = __expf(lgm[n] - mm); sm += mw[n];
            }
            const float ra = 1.f / sa, rm = 1.f / sm;
#pragma unroll
            for (int n = 0; n < NB; ++n) { aw[n] *= ra; mw[n] *= rm; }
        }

        f32x4 oa = (f32x4)(0.f), om = (f32x4)(0.f);
#pragma unroll
        for (int n = 0; n < NB; ++n) {
            oa += aw[n] * v[n];
            om += mw[n] * v[n];
        }
        *reinterpret_cast<f32x4*>(out + rb)           = oa;
        *reinterpret_cast<f32x4*>(out + nStride + rb) = om;
    };

    load_row(vA, rowbase(0));
#pragma unroll 1
    for (int i = 0; i < rpb; i += 2) {
        // prefetch row i+1 while row i's tail runs (loads survive barriers)
        load_row(vB, rowbase(i + 1 < rpb ? i + 1 : rpb - 1));
        process(vA, red[0], totl[0], rowbase(i));
        // prefetch row i+2 while row i+1's tail runs (clamped load is an L1 hit)
        load_row(vA, rowbase(i + 2 < rpb ? i + 2 : rpb - 1));
        if (i + 1 < rpb) process(vB, red[1], totl[1], rowbase(i + 1));
    }
}

extern "C" void kernel_launch(void* const* d_in, const int* in_sizes, int n_in,
                              void* d_out, int out_size, void* d_ws, size_t ws_size,
                              hipStream_t stream)
{
    const float* blocks  = (const float*)d_in[0];
    const float* partial = (const float*)d_in[1];
    const float* qa      = (const float*)d_in[2];
    const float* qm      = (const float*)d_in[3];
    const float* wa      = (const float*)d_in[4];
    const float* wm      = (const float*)d_in[5];
    float* out = (float*)d_out;

    const int D  = in_sizes[2];          // 2048
    const int BT = in_sizes[1] / D;      // B*T = 8192

    dim3 grid(NBLK), block(THREADS);
    hipLaunchKernelGGL(block_attn_res_kernel, grid, block, 0, stream,
                       blocks, partial, qa, qm, wa, wm, out, BT);
}

// Round 8
// 140.241 us; speedup vs baseline: 1.2613x; 1.2613x over previous
//
#include <hip/hip_runtime.h>

#define NB 8          // 7 full blocks + 1 partial block
#define DDIM 2048
#define THREADS 512
#define NBLK 1024     // 2 resident/CU + refill queue; rpb = 8192/1024 = 8
#define NWAVES (THREADS / 64)

typedef float f32x4 __attribute__((ext_vector_type(4)));

// 64-lane f32 add-reduction via DPP (VALU pipe, no DS ops). Total in lane 63.
__device__ __forceinline__ float wave_sum64(float x) {
    int t;
    t = __builtin_amdgcn_update_dpp(0, __float_as_int(x), 0x111, 0xf, 0xf, false); // row_shr:1
    x += __int_as_float(t);
    t = __builtin_amdgcn_update_dpp(0, __float_as_int(x), 0x112, 0xf, 0xf, false); // row_shr:2
    x += __int_as_float(t);
    t = __builtin_amdgcn_update_dpp(0, __float_as_int(x), 0x114, 0xf, 0xf, false); // row_shr:4
    x += __int_as_float(t);
    t = __builtin_amdgcn_update_dpp(0, __float_as_int(x), 0x118, 0xf, 0xf, false); // row_shr:8
    x += __int_as_float(t);
    t = __builtin_amdgcn_update_dpp(0, __float_as_int(x), 0x142, 0xa, 0xf, false); // row_bcast:15
    x += __int_as_float(t);
    t = __builtin_amdgcn_update_dpp(0, __float_as_int(x), 0x143, 0xc, 0xf, false); // row_bcast:31
    x += __int_as_float(t);
    return x;
}

// Orders LDS only — does NOT drain vmcnt, so prefetch loads stay in flight
// across it (unlike __syncthreads, which emits s_waitcnt vmcnt(0)).
__device__ __forceinline__ void barrier_lgkm() {
    asm volatile("s_waitcnt lgkmcnt(0)" ::: "memory");
    __builtin_amdgcn_s_barrier();
}

__global__ __launch_bounds__(THREADS, 4)   // cap 128 VGPR -> 2 blocks/CU
void block_attn_res_kernel(
    const float* __restrict__ blocks,   // [7, B*T, D]
    const float* __restrict__ partial,  // [B*T, D]
    const float* __restrict__ qa,
    const float* __restrict__ qm,
    const float* __restrict__ wa,
    const float* __restrict__ wm,
    float* __restrict__ out,            // h_attn [B*T*D] then h_mlp [B*T*D]
    int BT)
{
    const int tid = threadIdx.x;
    const int b   = blockIdx.x;
    const int c   = tid * 4;                  // this thread's 4 contiguous cols
    const size_t nStride = (size_t)BT * DDIM;
    const int rpb = BT / NBLK;                // rows per block (8)

    __shared__ float red[NWAVES * 24];
    __shared__ float totl[24];

    const f32x4 qwa = *reinterpret_cast<const f32x4*>(qa + c) *
                      *reinterpret_cast<const f32x4*>(wa + c);
    const f32x4 qwm = *reinterpret_cast<const f32x4*>(qm + c) *
                      *reinterpret_cast<const f32x4*>(wm + c);

    f32x4 vA[NB], vB[NB];

    auto rowbase = [&](int i) -> size_t {
        return (size_t)(i * NBLK + b) * DDIM + c;
    };
    auto load_row = [&](f32x4* v, size_t rb) {
#pragma unroll
        for (int n = 0; n < NB; ++n) {
            const float* src = (n < NB - 1) ? (blocks + (size_t)n * nStride + rb)
                                            : (partial + rb);
            v[n] = *reinterpret_cast<const f32x4*>(src);
        }
    };

    const int wave = tid >> 6;
    const bool is63 = (tid & 63) == 63;

    auto process = [&](const f32x4* v, size_t rb) {
        // stats: fold wave-reduced partials straight into LDS (no 24-wide arrays)
#pragma unroll
        for (int n = 0; n < NB; ++n) {
            float s = 0.f, pa = 0.f, pm = 0.f;
#pragma unroll
            for (int j = 0; j < 4; ++j) {
                s  += v[n][j] * v[n][j];
                pa += qwa[j]  * v[n][j];
                pm += qwm[j]  * v[n][j];
            }
            s  = wave_sum64(s);
            pa = wave_sum64(pa);
            pm = wave_sum64(pm);
            if (is63) {
                red[wave * 24 + n]      = s;
                red[wave * 24 + 8 + n]  = pa;
                red[wave * 24 + 16 + n] = pm;
            }
        }
        barrier_lgkm();
        if (tid < 24) {
            float s = 0.f;
#pragma unroll
            for (int w = 0; w < NWAVES; ++w) s += red[w * 24 + tid];
            totl[tid] = s;
        }
        barrier_lgkm();

        // softmax logits (redundant per thread; 24 broadcast LDS reads)
        const float inv_sqrt_d = rsqrtf((float)DDIM);
        float lga[NB], lgm[NB];
#pragma unroll
        for (int n = 0; n < NB; ++n) {
            float rms = rsqrtf(totl[n] * (1.0f / DDIM) + 1e-6f);
            lga[n] = totl[8 + n]  * rms * inv_sqrt_d;
            lgm[n] = totl[16 + n] * rms * inv_sqrt_d;
        }
        float ma = lga[0], mm = lgm[0];
#pragma unroll
        for (int n = 1; n < NB; ++n) { ma = fmaxf(ma, lga[n]); mm = fmaxf(mm, lgm[n]); }

        // unnormalized combine; divide by softmax denom at the end
        f32x4 oa = (f32x4)(0.f), om = (f32x4)(0.f);
        float sa = 0.f, sm = 0.f;
#pragma unroll
        for (int n = 0; n < NB; ++n) {
            float ea = __expf(lga[n] - ma); sa += ea; oa += ea * v[n];
            float em = __expf(lgm[n] - mm); sm += em; om += em * v[n];
        }
        oa *= (1.f / sa);
        om *= (1.f / sm);
        *reinterpret_cast<f32x4*>(out + rb)           = oa;
        *reinterpret_cast<f32x4*>(out + nStride + rb) = om;
    };

    load_row(vA, rowbase(0));
#pragma unroll 1
    for (int i = 0; i < rpb; i += 2) {
        if (i + 1 < rpb) load_row(vB, rowbase(i + 1));   // prefetch across tail(i)
        process(vA, rowbase(i));
        if (i + 1 < rpb) {
            if (i + 2 < rpb) load_row(vA, rowbase(i + 2)); // prefetch across tail(i+1)
            process(vB, rowbase(i + 1));
        }
    }
}

extern "C" void kernel_launch(void* const* d_in, const int* in_sizes, int n_in,
                              void* d_out, int out_size, void* d_ws, size_t ws_size,
                              hipStream_t stream)
{
    const float* blocks  = (const float*)d_in[0];
    const float* partial = (const float*)d_in[1];
    const float* qa      = (const float*)d_in[2];
    const float* qm      = (const float*)d_in[3];
    const float* wa      = (const float*)d_in[4];
    const float* wm      = (const float*)d_in[5];
    float* out = (float*)d_out;

    const int D  = in_sizes[2];          // 2048
    const int BT = in_sizes[1] / D;      // B*T = 8192

    dim3 grid(NBLK), block(THREADS);
    hipLaunchKernelGGL(block_attn_res_kernel, grid, block, 0, stream,
                       blocks, partial, qa, qm, wa, wm, out, BT);
}

// Round 9
// 138.393 us; speedup vs baseline: 1.2782x; 1.0134x over previous
//
#include <hip/hip_runtime.h>

#define NB 8          // 7 full blocks + 1 partial block
#define DDIM 2048
#define THREADS 256
#define NROWS 4       // rows per block, statically unrolled ping-pong
#define NWAVES (THREADS / 64)

typedef float f32x4 __attribute__((ext_vector_type(4)));

// 64-lane f32 add-reduction via DPP (VALU pipe, no DS ops). Total in lane 63.
__device__ __forceinline__ float wave_sum64(float x) {
    int t;
    t = __builtin_amdgcn_update_dpp(0, __float_as_int(x), 0x111, 0xf, 0xf, false); // row_shr:1
    x += __int_as_float(t);
    t = __builtin_amdgcn_update_dpp(0, __float_as_int(x), 0x112, 0xf, 0xf, false); // row_shr:2
    x += __int_as_float(t);
    t = __builtin_amdgcn_update_dpp(0, __float_as_int(x), 0x114, 0xf, 0xf, false); // row_shr:4
    x += __int_as_float(t);
    t = __builtin_amdgcn_update_dpp(0, __float_as_int(x), 0x118, 0xf, 0xf, false); // row_shr:8
    x += __int_as_float(t);
    t = __builtin_amdgcn_update_dpp(0, __float_as_int(x), 0x142, 0xa, 0xf, false); // row_bcast:15
    x += __int_as_float(t);
    t = __builtin_amdgcn_update_dpp(0, __float_as_int(x), 0x143, 0xc, 0xf, false); // row_bcast:31
    x += __int_as_float(t);
    return x;
}

// Orders LDS only — does NOT drain vmcnt, so prefetch loads for the next row
// stay in flight across it (unlike __syncthreads, which emits vmcnt(0)).
__device__ __forceinline__ void barrier_lgkm() {
    asm volatile("s_waitcnt lgkmcnt(0)" ::: "memory");
    __builtin_amdgcn_s_barrier();
}

__global__ __launch_bounds__(THREADS, 2)   // cap 256 VGPR: dbuf fits, NO spill
void block_attn_res_kernel(
    const float* __restrict__ blocks,   // [7, B*T, D]
    const float* __restrict__ partial,  // [B*T, D]
    const float* __restrict__ qa,
    const float* __restrict__ qm,
    const float* __restrict__ wa,
    const float* __restrict__ wm,
    float* __restrict__ out,            // h_attn [B*T*D] then h_mlp [B*T*D]
    int BT)
{
    const int tid = threadIdx.x;
    const int b   = blockIdx.x;
    const int nblk = gridDim.x;               // BT / NROWS
    // two fully-coalesced column groups: [4*tid, 4*tid+4) and +D/2
    const int c0 = tid * 4;
    const int c1 = c0 + DDIM / 2;
    const size_t nStride = (size_t)BT * DDIM;

    __shared__ float red[2][NWAVES * 24];
    __shared__ float totl[2][24];

    const f32x4 qwa0 = *reinterpret_cast<const f32x4*>(qa + c0) *
                       *reinterpret_cast<const f32x4*>(wa + c0);
    const f32x4 qwa1 = *reinterpret_cast<const f32x4*>(qa + c1) *
                       *reinterpret_cast<const f32x4*>(wa + c1);
    const f32x4 qwm0 = *reinterpret_cast<const f32x4*>(qm + c0) *
                       *reinterpret_cast<const f32x4*>(wm + c0);
    const f32x4 qwm1 = *reinterpret_cast<const f32x4*>(qm + c1) *
                       *reinterpret_cast<const f32x4*>(wm + c1);

    f32x4 vA[NB][2], vB[NB][2];

    auto rowbase = [&](int g) -> size_t {
        return (size_t)(g * nblk + b) * DDIM;
    };
    auto load_row = [&](f32x4 (*v)[2], size_t rb) {
#pragma unroll
        for (int n = 0; n < NB; ++n) {
            const float* src = (n < NB - 1) ? (blocks + (size_t)n * nStride + rb)
                                            : (partial + rb);
            v[n][0] = *reinterpret_cast<const f32x4*>(src + c0);
            v[n][1] = *reinterpret_cast<const f32x4*>(src + c1);
        }
    };

    const int wave = tid >> 6;
    const bool is63 = (tid & 63) == 63;

    auto process = [&](const f32x4 (*v)[2], float* redb, float* totb, size_t rb) {
        // per-n stats, wave-reduced, folded straight into LDS
#pragma unroll
        for (int n = 0; n < NB; ++n) {
            float s = 0.f, pa = 0.f, pm = 0.f;
#pragma unroll
            for (int j = 0; j < 4; ++j) {
                s  += v[n][0][j] * v[n][0][j] + v[n][1][j] * v[n][1][j];
                pa += qwa0[j] * v[n][0][j] + qwa1[j] * v[n][1][j];
                pm += qwm0[j] * v[n][0][j] + qwm1[j] * v[n][1][j];
            }
            s  = wave_sum64(s);
            pa = wave_sum64(pa);
            pm = wave_sum64(pm);
            if (is63) {
                redb[wave * 24 + n]      = s;
                redb[wave * 24 + 8 + n]  = pa;
                redb[wave * 24 + 16 + n] = pm;
            }
        }
        barrier_lgkm();   // LDS-order only; next-row prefetch stays in flight

        // all threads: sum 4 wave-partials (vectorized broadcast reads), softmax
        float t24[24];
        {
            const f32x4* r4 = reinterpret_cast<const f32x4*>(redb);
#pragma unroll
            for (int g = 0; g < 6; ++g) {
                f32x4 x = r4[g] + r4[6 + g] + r4[12 + g] + r4[18 + g];
                t24[4 * g + 0] = x.x; t24[4 * g + 1] = x.y;
                t24[4 * g + 2] = x.z; t24[4 * g + 3] = x.w;
            }
        }
        (void)totb;

        const float inv_sqrt_d = rsqrtf((float)DDIM);
        float lga[NB], lgm[NB];
#pragma unroll
        for (int n = 0; n < NB; ++n) {
            float rms = rsqrtf(t24[n] * (1.0f / DDIM) + 1e-6f);
            lga[n] = t24[8 + n]  * rms * inv_sqrt_d;
            lgm[n] = t24[16 + n] * rms * inv_sqrt_d;
        }
        float ma = lga[0], mm = lgm[0];
#pragma unroll
        for (int n = 1; n < NB; ++n) { ma = fmaxf(ma, lga[n]); mm = fmaxf(mm, lgm[n]); }

        f32x4 oa0 = (f32x4)(0.f), oa1 = (f32x4)(0.f);
        f32x4 om0 = (f32x4)(0.f), om1 = (f32x4)(0.f);
        float sa = 0.f, sm = 0.f;
#pragma unroll
        for (int n = 0; n < NB; ++n) {
            float ea = __expf(lga[n] - ma); sa += ea;
            float em = __expf(lgm[n] - mm); sm += em;
            oa0 += ea * v[n][0]; oa1 += ea * v[n][1];
            om0 += em * v[n][0]; om1 += em * v[n][1];
        }
        const float ra = 1.f / sa, rm = 1.f / sm;
        *reinterpret_cast<f32x4*>(out + rb + c0)            = oa0 * ra;
        *reinterpret_cast<f32x4*>(out + rb + c1)            = oa1 * ra;
        *reinterpret_cast<f32x4*>(out + nStride + rb + c0)  = om0 * rm;
        *reinterpret_cast<f32x4*>(out + nStride + rb + c1)  = om1 * rm;
    };

    // statically-unrolled 4-row ping-pong pipeline
    load_row(vA, rowbase(0));
    load_row(vB, rowbase(1));                 // prefetch: survives row0's barrier
    process(vA, red[0], totl[0], rowbase(0));
    load_row(vA, rowbase(2));                 // prefetch across row1's tail
    process(vB, red[1], totl[1], rowbase(1));
    load_row(vB, rowbase(3));                 // prefetch across row2's tail
    process(vA, red[0], totl[0], rowbase(2));
    process(vB, red[1], totl[1], rowbase(3));
}

extern "C" void kernel_launch(void* const* d_in, const int* in_sizes, int n_in,
                              void* d_out, int out_size, void* d_ws, size_t ws_size,
                              hipStream_t stream)
{
    const float* blocks  = (const float*)d_in[0];
    const float* partial = (const float*)d_in[1];
    const float* qa      = (const float*)d_in[2];
    const float* qm      = (const float*)d_in[3];
    const float* wa      = (const float*)d_in[4];
    const float* wm      = (const float*)d_in[5];
    float* out = (float*)d_out;

    const int D  = in_sizes[2];          // 2048
    const int BT = in_sizes[1] / D;      // B*T = 8192

    dim3 grid(BT / NROWS), block(THREADS);
    hipLaunchKernelGGL(block_attn_res_kernel, grid, block, 0, stream,
                       blocks, partial, qa, qm, wa, wm, out, BT);
}

// Round 10
// 120.592 us; speedup vs baseline: 1.4669x; 1.1476x over previous
//
#include <hip/hip_runtime.h>

#define NB 8          // 7 full blocks + 1 partial block
#define DDIM 2048
#define THREADS 256

typedef float f32x4 __attribute__((ext_vector_type(4)));

// 64-lane f32 add-reduction via DPP (VALU pipe, no DS ops). Total in lane 63.
__device__ __forceinline__ float wave_sum64(float x) {
    int t;
    t = __builtin_amdgcn_update_dpp(0, __float_as_int(x), 0x111, 0xf, 0xf, false); // row_shr:1
    x += __int_as_float(t);
    t = __builtin_amdgcn_update_dpp(0, __float_as_int(x), 0x112, 0xf, 0xf, false); // row_shr:2
    x += __int_as_float(t);
    t = __builtin_amdgcn_update_dpp(0, __float_as_int(x), 0x114, 0xf, 0xf, false); // row_shr:4
    x += __int_as_float(t);
    t = __builtin_amdgcn_update_dpp(0, __float_as_int(x), 0x118, 0xf, 0xf, false); // row_shr:8
    x += __int_as_float(t);
    t = __builtin_amdgcn_update_dpp(0, __float_as_int(x), 0x142, 0xa, 0xf, false); // row_bcast:15
    x += __int_as_float(t);
    t = __builtin_amdgcn_update_dpp(0, __float_as_int(x), 0x143, 0xc, 0xf, false); // row_bcast:31
    x += __int_as_float(t);
    return x;
}

__global__ __launch_bounds__(THREADS, 4)   // cap at 128 VGPR -> 4 blocks/CU
void block_attn_res_kernel(
    const float* __restrict__ blocks,   // [7, B*T, D]
    const float* __restrict__ partial,  // [B*T, D]
    const float* __restrict__ qa,
    const float* __restrict__ qm,
    const float* __restrict__ wa,
    const float* __restrict__ wm,
    float* __restrict__ out,            // h_attn [B*T*D] then h_mlp [B*T*D]
    int BT)
{
    const int row = blockIdx.x;
    const int tid = threadIdx.x;
    // two fully-coalesced column groups: [4*tid, 4*tid+4) and +D/2
    const int c0 = tid * 4;
    const int c1 = c0 + DDIM / 2;

    const size_t rowBase = (size_t)row * DDIM;
    const size_t nStride = (size_t)BT * DDIM;

    // per-thread q*w slice (16 VGPR)
    f32x4 qw[2][2];   // [a/m][half]
    {
        const f32x4 qa0 = *reinterpret_cast<const f32x4*>(qa + c0);
        const f32x4 qa1 = *reinterpret_cast<const f32x4*>(qa + c1);
        const f32x4 wa0 = *reinterpret_cast<const f32x4*>(wa + c0);
        const f32x4 wa1 = *reinterpret_cast<const f32x4*>(wa + c1);
        const f32x4 qm0 = *reinterpret_cast<const f32x4*>(qm + c0);
        const f32x4 qm1 = *reinterpret_cast<const f32x4*>(qm + c1);
        const f32x4 wm0 = *reinterpret_cast<const f32x4*>(wm + c0);
        const f32x4 wm1 = *reinterpret_cast<const f32x4*>(wm + c1);
        qw[0][0] = qa0 * wa0;  qw[0][1] = qa1 * wa1;
        qw[1][0] = qm0 * wm0;  qw[1][1] = qm1 * wm1;
    }

    // register-resident V slice: 8 n-rows x 8 floats = 64 VGPR
    f32x4 v[NB][2];
    float ss[NB], da[NB], dm[NB];

#pragma unroll
    for (int n = 0; n < NB; ++n) {
        const float* src = (n < NB - 1) ? (blocks + (size_t)n * nStride + rowBase)
                                        : (partial + rowBase);
        v[n][0] = *reinterpret_cast<const f32x4*>(src + c0);
        v[n][1] = *reinterpret_cast<const f32x4*>(src + c1);
        float s = 0.f, pa = 0.f, pm = 0.f;
#pragma unroll
        for (int k = 0; k < 2; ++k) {
#pragma unroll
            for (int j = 0; j < 4; ++j) {
                s  += v[n][k][j]  * v[n][k][j];
                pa += qw[0][k][j] * v[n][k][j];
                pm += qw[1][k][j] * v[n][k][j];
            }
        }
        ss[n] = s; da[n] = pa; dm[n] = pm;
    }

    // wave-level reduction entirely on the VALU pipe (DPP); result in lane 63
#pragma unroll
    for (int n = 0; n < NB; ++n) {
        ss[n] = wave_sum64(ss[n]);
        da[n] = wave_sum64(da[n]);
        dm[n] = wave_sum64(dm[n]);
    }

    // cross-wave combine: 24 floats per wave, [wave][24] layout
    __shared__ float red[4 * 24];
    const int wave = tid >> 6;
    if ((tid & 63) == 63) {
#pragma unroll
        for (int n = 0; n < NB; ++n) {
            red[wave * 24 + n]      = ss[n];
            red[wave * 24 + 8 + n]  = da[n];
            red[wave * 24 + 16 + n] = dm[n];
        }
    }
    __syncthreads();

    // sum the 4 per-wave partial vectors with vector ds_read_b128 (broadcast)
    float tot[24];
    {
        const f32x4* r4 = reinterpret_cast<const f32x4*>(red);
#pragma unroll
        for (int g = 0; g < 6; ++g) {
            f32x4 a = r4[g], b = r4[6 + g], c = r4[12 + g], d = r4[18 + g];
            f32x4 s4 = a + b + c + d;
            tot[4 * g + 0] = s4.x;
            tot[4 * g + 1] = s4.y;
            tot[4 * g + 2] = s4.z;
            tot[4 * g + 3] = s4.w;
        }
    }

    float aw[NB], mw[NB];
    {
        const float inv_sqrt_d = rsqrtf((float)DDIM);
        float lga[NB], lgm[NB];
#pragma unroll
        for (int n = 0; n < NB; ++n) {
            float rms = rsqrtf(tot[n] * (1.0f / DDIM) + 1e-6f);
            lga[n] = tot[8 + n]  * rms * inv_sqrt_d;
            lgm[n] = tot[16 + n] * rms * inv_sqrt_d;
        }
        float ma = lga[0], mm = lgm[0];
#pragma unroll
        for (int n = 1; n < NB; ++n) { ma = fmaxf(ma, lga[n]); mm = fmaxf(mm, lgm[n]); }
        float sa = 0.f, sm = 0.f;
#pragma unroll
        for (int n = 0; n < NB; ++n) {
            aw[n] = __expf(lga[n] - ma); sa += aw[n];
            mw[n] = __expf(lgm[n] - mm); sm += mw[n];
        }
        const float ra = 1.f / sa, rm = 1.f / sm;
#pragma unroll
        for (int n = 0; n < NB; ++n) { aw[n] *= ra; mw[n] *= rm; }
    }

    // combine straight from registers — V read from HBM exactly once
    f32x4 oa[2], om[2];
#pragma unroll
    for (int k = 0; k < 2; ++k) {
        oa[k] = (f32x4)(0.f);
        om[k] = (f32x4)(0.f);
    }
#pragma unroll
    for (int n = 0; n < NB; ++n) {
#pragma unroll
        for (int k = 0; k < 2; ++k) {
            oa[k] += aw[n] * v[n][k];
            om[k] += mw[n] * v[n][k];
        }
    }

    // NT stores ONLY (loads stay cached): write around L2 so the output
    // stream doesn't evict/steal L2 resources from the 537 MB read stream.
    float* outa = out + rowBase;
    float* outm = out + nStride + rowBase;
    __builtin_nontemporal_store(oa[0], reinterpret_cast<f32x4*>(outa + c0));
    __builtin_nontemporal_store(oa[1], reinterpret_cast<f32x4*>(outa + c1));
    __builtin_nontemporal_store(om[0], reinterpret_cast<f32x4*>(outm + c0));
    __builtin_nontemporal_store(om[1], reinterpret_cast<f32x4*>(outm + c1));
}

extern "C" void kernel_launch(void* const* d_in, const int* in_sizes, int n_in,
                              void* d_out, int out_size, void* d_ws, size_t ws_size,
                              hipStream_t stream)
{
    const float* blocks  = (const float*)d_in[0];
    const float* partial = (const float*)d_in[1];
    const float* qa      = (const float*)d_in[2];
    const float* qm      = (const float*)d_in[3];
    const float* wa      = (const float*)d_in[4];
    const float* wm      = (const float*)d_in[5];
    float* out = (float*)d_out;

    const int D  = in_sizes[2];          // 2048
    const int BT = in_sizes[1] / D;      // B*T = 8192

    dim3 grid(BT), block(THREADS);
    hipLaunchKernelGGL(block_attn_res_kernel, grid, block, 0, stream,
                       blocks, partial, qa, qm, wa, wm, out, BT);
}